// Round 2
// baseline (587.133 us; speedup 1.0000x reference)
//
#include <hip/hip_runtime.h>
#include <math.h>

// Problem constants (from reference)
#define B_   1024
#define T_   64
#define F_   18
#define U_   128
#define U3_  384   // 3*U
#define D_   64    // dense units

// One single-wave block (64 threads) per batch element; each lane owns 2
// hidden units (lane, lane+64).
//
// Key insight (verified exact in R1): the state table is indexed (id, b);
// step t only touches table[id_t, b], so per batch element the timesteps
// split into independent chains per id. The output depends only on h_new at
// t=63, i.e. only on timesteps where id_t == id_{63} (expected ~1.06 steps).
//
// Single-wave refinements: chain membership via __ballot (no LDS id scan),
// x_t read as wave-uniform scalar loads, h-nonzero test via __ballot
// (hz matvec is exactly 0 when h==0 — the common first-step case).
__global__ __launch_bounds__(64) void feedzai_sync_gru_kernel(
    const float* __restrict__ inputs,      // [B, T, F]
    const float* __restrict__ sync_states, // [NIDS, B, U]
    const float* __restrict__ kernel_,     // [F, 3U]
    const float* __restrict__ rec_kernel,  // [U, 3U]
    const float* __restrict__ bias,        // [3U]
    const float* __restrict__ dense_w,     // [U, 64]
    const float* __restrict__ dense_b,     // [64]
    const float* __restrict__ out_w,       // [64, 1]
    const float* __restrict__ out_b,       // [1]
    float* __restrict__ out)               // [B, 1]
{
    const int b    = blockIdx.x;
    const int lane = threadIdx.x;          // 0..63

    __shared__ float sh[U_];               // current hidden state (512 B)

    const float* inp_b = inputs + (size_t)b * T_ * F_;

    // Lane l holds the id at timestep l (column 0, stride F floats).
    const int sid_l   = (int)inp_b[lane * F_];
    const int id_last = __shfl(sid_l, T_ - 1, 64);
    unsigned long long chain = __ballot(sid_l == id_last);  // ≥1 bit (t=63)

    // Initial h for this chain = pristine sync_states[id_last, b, :].
    const float* hrow = sync_states + ((size_t)id_last * B_ + b) * U_;
    float h0 = hrow[lane];
    float h1 = hrow[lane + 64];
    sh[lane] = h0; sh[lane + 64] = h1;
    __syncthreads();

    // Bias columns for this lane's 2 units x 3 gates (hoisted, L1-resident).
    const float bz0 = bias[lane],           bz1 = bias[lane + 64];
    const float br0 = bias[U_ + lane],      br1 = bias[U_ + lane + 64];
    const float bh0 = bias[2 * U_ + lane],  bh1 = bias[2 * U_ + lane + 64];

    while (chain) {
        const int t = __ffsll((unsigned long long)chain) - 1;
        chain &= chain - 1;

        // hz == 0 exactly when h == 0 (register-resident test, no LDS).
        const bool hnz = (__ballot(h0 != 0.0f || h1 != 0.0f) != 0ull);

        const float* xrow = inp_b + t * F_;  // wave-uniform -> scalar loads

        // xz = x_t @ kernel + bias (same accumulation order as R1: exact)
        float z0 = bz0, z1 = bz1, r0 = br0, r1 = br1, g0 = bh0, g1 = bh1;
        #pragma unroll
        for (int f = 0; f < F_; ++f) {
            const float xv = xrow[f];
            const float* kf = kernel_ + f * U3_;
            z0 += xv * kf[lane];            z1 += xv * kf[lane + 64];
            r0 += xv * kf[U_ + lane];       r1 += xv * kf[U_ + lane + 64];
            g0 += xv * kf[2 * U_ + lane];   g1 += xv * kf[2 * U_ + lane + 64];
        }

        // hz = h @ rec_kernel
        float hz0 = 0.f, hz1 = 0.f, hr0 = 0.f, hr1 = 0.f, hg0 = 0.f, hg1 = 0.f;
        if (hnz) {
            for (int k = 0; k < U_; ++k) {
                const float hv = sh[k];    // broadcast read, conflict-free
                const float* rk = rec_kernel + k * U3_;
                hz0 += hv * rk[lane];           hz1 += hv * rk[lane + 64];
                hr0 += hv * rk[U_ + lane];      hr1 += hv * rk[U_ + lane + 64];
                hg0 += hv * rk[2 * U_ + lane];  hg1 += hv * rk[2 * U_ + lane + 64];
            }
        }

        // GRU cell (keras hard_sigmoid + tanh)
        const float zz0 = fminf(fmaxf(0.2f * (z0 + hz0) + 0.5f, 0.f), 1.f);
        const float zz1 = fminf(fmaxf(0.2f * (z1 + hz1) + 0.5f, 0.f), 1.f);
        const float rr0 = fminf(fmaxf(0.2f * (r0 + hr0) + 0.5f, 0.f), 1.f);
        const float rr1 = fminf(fmaxf(0.2f * (r1 + hr1) + 0.5f, 0.f), 1.f);
        const float hh0 = tanhf(g0 + rr0 * hg0);
        const float hh1 = tanhf(g1 + rr1 * hg1);
        h0 = zz0 * h0 + (1.f - zz0) * hh0;
        h1 = zz1 * h1 + (1.f - zz1) * hh1;

        __syncthreads();                   // all sh reads of this step done
        sh[lane] = h0; sh[lane + 64] = h1;
        __syncthreads();                   // new h visible
    }

    // Dense(128->64) + relu, then dot with out_w, sigmoid. All 64 lanes busy.
    float dv = dense_b[lane];
    for (int k = 0; k < U_; ++k)
        dv += sh[k] * dense_w[k * D_ + lane];   // coalesced across lanes
    dv = fmaxf(dv, 0.f) * out_w[lane];

    #pragma unroll
    for (int off = 32; off > 0; off >>= 1)
        dv += __shfl_down(dv, off, 64);

    if (lane == 0)
        out[b] = 1.0f / (1.0f + expf(-(dv + out_b[0])));
}

extern "C" void kernel_launch(void* const* d_in, const int* in_sizes, int n_in,
                              void* d_out, int out_size, void* d_ws, size_t ws_size,
                              hipStream_t stream) {
    const float* inputs      = (const float*)d_in[0];
    const float* sync_states = (const float*)d_in[1];
    const float* kernel_     = (const float*)d_in[2];
    const float* rec_kernel  = (const float*)d_in[3];
    const float* bias        = (const float*)d_in[4];
    const float* dense_w     = (const float*)d_in[5];
    const float* dense_b     = (const float*)d_in[6];
    const float* out_w       = (const float*)d_in[7];
    const float* out_b       = (const float*)d_in[8];
    float* out = (float*)d_out;

    feedzai_sync_gru_kernel<<<dim3(B_), dim3(64), 0, stream>>>(
        inputs, sync_states, kernel_, rec_kernel, bias,
        dense_w, dense_b, out_w, out_b, out);
}